// Round 1
// 327.292 us; speedup vs baseline: 1.0041x; 1.0041x over previous
//
#include <hip/hip_runtime.h>

// out[b,n] = sum_e c[b,n,e] * s[b,e];  B=32, N=8192, E=256, fp32.
// R1-R5 history: NT loads + 1024 blocks = 327.6us; reverse sweep neutral
// (=> c is NOT L3-resident at launch; the 1GiB harness fill scrubs it).
// R6 theory: dur_us includes harness re-poison (fills show up in rocprof at
// 162-168us each; our kernel must be <162us). Kernel portion ~80us fits
// 268MB cold read + ~256MB forced writeback of the fill's dirty L3 lines.
// R6 single change vs R5: stream loads via inline asm with full CPol
// (sc0 sc1 nt = system-scope non-temporal) to suppress allocation in
// L1/L2 and hint no-allocate as far down as policy allows, so read misses
// stop evicting dirty fill lines. Predict: dur -30..-40us if allocation is
// policy-gated; neutral if Infinity Cache is memory-side mandatory-allocate
// (which would mean the kernel is at its effective-traffic roofline).

typedef float f32x4 __attribute__((ext_vector_type(4)));

constexpr int kLogN        = 13;   // N = 8192 rows per batch
constexpr int kF4PerRow    = 64;   // E/4
constexpr int kRowsPerIter = 8;    // rows per wave per grid-stride step
constexpr int kBlocks      = 1024; // 4 blocks/CU
constexpr int kThreads     = 256;  // 4 waves/block -> 4096 waves

__device__ __forceinline__ float lane_merge(float a, float b, int sel, int off) {
    float send = sel ? a : b;
    float recv = __shfl_xor(send, off, 64);
    return (sel ? b : a) + recv;
}

// System-scope non-temporal 16B stream load. offset is a textual immediate
// (13-bit signed on gfx950 global_*; we keep it <= 3072).
#define STREAM_LD(dst, base, OFF)                                             \
    asm volatile("global_load_dwordx4 %0, %1, off offset:" #OFF " sc0 sc1 nt" \
                 : "=v"(dst) : "v"(base))

__global__ __launch_bounds__(kThreads) void ctx_seg_score_kernel(
    const float* __restrict__ c,   // [B*N, E]
    const float* __restrict__ s,   // [B, E]
    float* __restrict__ out,       // [B*N]
    int total_rows)                // B*N = 262144
{
    const int lane   = threadIdx.x & 63;
    const int gwave  = (blockIdx.x * blockDim.x + threadIdx.x) >> 6;
    const int nwaves = (gridDim.x * blockDim.x) >> 6;   // 4096

    const f32x4* __restrict__ c4p = reinterpret_cast<const f32x4*>(c);
    const float4* __restrict__ s4p = reinterpret_cast<const float4*>(s);

    const int sel1 = lane & 1;
    const int sel2 = (lane >> 1) & 1;
    const int sel4 = (lane >> 2) & 1;

    const int rowsPerSweep = nwaves * kRowsPerIter;        // 32768 rows = 32MB
    const int iters = total_rows / rowsPerSweep;           // 8 (exact)

    // Reverse sweep kept from R5 (neutral, can't hurt).
    for (int j = iters - 1; j >= 0; --j) {
        const int r0 = j * rowsPerSweep + gwave * kRowsPerIter;

        const int b = r0 >> kLogN;            // 8 | 8192 -> one batch per octet
        const float4 s4 = s4p[b * kF4PerRow + lane];

        // 8 independent coalesced 1-KiB wave loads, system-scope + nt.
        // Two base pointers so every offset fits the 13-bit signed imm.
        const f32x4* base0 = &c4p[(size_t)r0 * kF4PerRow + lane];
        const f32x4* base1 = base0 + 4 * kF4PerRow;   // +4 rows = +4096 B

        f32x4 a[kRowsPerIter];
        STREAM_LD(a[0], base0, 0);
        STREAM_LD(a[1], base0, 1024);
        STREAM_LD(a[2], base0, 2048);
        STREAM_LD(a[3], base0, 3072);
        STREAM_LD(a[4], base1, 0);
        STREAM_LD(a[5], base1, 1024);
        STREAM_LD(a[6], base1, 2048);
        STREAM_LD(a[7], base1, 3072);

        // Inline-asm loads get no compiler waitcnt: drain explicitly, and
        // fence the scheduler so FMAs can't hoist above the wait (rule #18).
        asm volatile("s_waitcnt vmcnt(0)" ::: "memory");
        __builtin_amdgcn_sched_barrier(0);

        float p[kRowsPerIter];
        #pragma unroll
        for (int u = 0; u < kRowsPerIter; ++u)
            p[u] = fmaf(a[u].x, s4.x,
                   fmaf(a[u].y, s4.y,
                   fmaf(a[u].z, s4.z, a[u].w * s4.w)));

        // Merge tree: 7 shuffles -> lane l owns row (l&7) summed over octet.
        float v01 = lane_merge(p[0], p[1], sel1, 1);
        float v23 = lane_merge(p[2], p[3], sel1, 1);
        float v45 = lane_merge(p[4], p[5], sel1, 1);
        float v67 = lane_merge(p[6], p[7], sel1, 1);
        float w03 = lane_merge(v01, v23, sel2, 2);
        float w47 = lane_merge(v45, v67, sel2, 2);
        float v   = lane_merge(w03, w47, sel4, 4);

        // Butterfly over remaining lane bits: 3 shuffles.
        v += __shfl_xor(v, 8, 64);
        v += __shfl_xor(v, 16, 64);
        v += __shfl_xor(v, 32, 64);

        // lane l (l<8) holds the total for row r0+l: 32 B coalesced store.
        if (lane < kRowsPerIter)
            out[r0 + lane] = v;
    }
}

extern "C" void kernel_launch(void* const* d_in, const int* in_sizes, int n_in,
                              void* d_out, int out_size, void* d_ws, size_t ws_size,
                              hipStream_t stream) {
    const float* c = (const float*)d_in[0];
    const float* s = (const float*)d_in[1];
    float* out = (float*)d_out;

    ctx_seg_score_kernel<<<kBlocks, kThreads, 0, stream>>>(c, s, out, out_size);
}